// Round 5
// baseline (276.648 us; speedup 1.0000x reference)
//
#include <hip/hip_runtime.h>

#define D_MODEL 1024
#define NUM_HEADS 16
#define DH 64
#define B_SZ 2
#define T_SZ 2048
#define M_ROWS (B_SZ * T_SZ)   // 4096

typedef __bf16 bf16;
typedef __bf16 bf16x4 __attribute__((ext_vector_type(4)));
typedef __bf16 bf16x8 __attribute__((ext_vector_type(8)));
typedef float f32x4 __attribute__((ext_vector_type(4)));

__device__ __forceinline__ void async_copy16(const bf16* g, bf16* l) {
  __builtin_amdgcn_global_load_lds(
      (const __attribute__((address_space(1))) void*)g,
      (__attribute__((address_space(3))) void*)l, 16, 0, 0);
}

// ---------------------------------------------------------------------------
// 1. Cast fp32 -> bf16
// ---------------------------------------------------------------------------
#define NX (M_ROWS * D_MODEL / 4)
#define NW (D_MODEL * D_MODEL / 4)

__global__ __launch_bounds__(256) void cast_all(
    const float* __restrict__ X, const float* __restrict__ Wq,
    const float* __restrict__ Wk, const float* __restrict__ Wv,
    const float* __restrict__ Wo,
    bf16* __restrict__ Xb, bf16* __restrict__ Wqb, bf16* __restrict__ Wkb,
    bf16* __restrict__ Wvb, bf16* __restrict__ Wob) {
  int i = blockIdx.x * 256 + threadIdx.x;
  const float* s; bf16* d; int off;
  if (i < NX) {
    s = X; d = Xb; off = i;
  } else {
    int j = i - NX;
    int w = j >> 18;
    off = j & (NW - 1);
    if (w == 0)      { s = Wq; d = Wqb; }
    else if (w == 1) { s = Wk; d = Wkb; }
    else if (w == 2) { s = Wv; d = Wvb; }
    else             { s = Wo; d = Wob; }
  }
  float4 v = ((const float4*)s)[off];
  bf16x4 o;
  o[0] = (bf16)v.x; o[1] = (bf16)v.y; o[2] = (bf16)v.z; o[3] = (bf16)v.w;
  ((bf16x4*)d)[off] = o;
}

// ---------------------------------------------------------------------------
// 2. QKV GEMM, m97 structure (unchanged)
// ---------------------------------------------------------------------------
__global__ __launch_bounds__(256) void qkv_gemm(
    const bf16* __restrict__ Xb,
    const bf16* __restrict__ Wqb, const bf16* __restrict__ Wkb,
    const bf16* __restrict__ Wvb,
    bf16* __restrict__ Q, bf16* __restrict__ K, bf16* __restrict__ V) {
  __shared__ bf16 As[128 * 32];
  __shared__ bf16 Bs[128 * 32];

  int tid = threadIdx.x;
  int wave = tid >> 6, lane = tid & 63;
  int wm = wave >> 1, wn = wave & 1;
  int l15 = lane & 15, quad = lane >> 4;

  int row0 = blockIdx.x * 128;
  int col0 = blockIdx.y * 128;
  int sel = col0 >> 10;
  int nb = col0 & 1023;
  const bf16* W; bf16* Out;
  if (sel == 0)      { W = Wqb; Out = Q; }
  else if (sel == 1) { W = Wkb; Out = K; }
  else               { W = Wvb; Out = V; }

  int srow = tid >> 2;
  int schunk = tid & 3;
  const bf16* Ag = Xb + (size_t)(row0 + srow) * D_MODEL + schunk * 8;
  const bf16* Bg = W + (size_t)(nb + srow) * D_MODEL + schunk * 8;
  bf16* Al0 = &As[srow * 32 + schunk * 8];
  bf16* Al1 = &As[(srow + 64) * 32 + schunk * 8];
  bf16* Bl0 = &Bs[srow * 32 + schunk * 8];
  bf16* Bl1 = &Bs[(srow + 64) * 32 + schunk * 8];

  f32x4 acc[4][4];
#pragma unroll
  for (int i = 0; i < 4; ++i)
#pragma unroll
    for (int j = 0; j < 4; ++j) acc[i][j] = (f32x4){0.f, 0.f, 0.f, 0.f};

  for (int k0 = 0; k0 < D_MODEL; k0 += 32) {
    async_copy16(Ag + k0, Al0);
    async_copy16(Ag + k0 + (size_t)64 * D_MODEL, Al1);
    async_copy16(Bg + k0, Bl0);
    async_copy16(Bg + k0 + (size_t)64 * D_MODEL, Bl1);
    __syncthreads();

    bf16x8 af[4], bfr[4];
#pragma unroll
    for (int i = 0; i < 4; ++i)
      af[i] = *(const bf16x8*)&As[(wm * 64 + i * 16 + l15) * 32 + quad * 8];
#pragma unroll
    for (int j = 0; j < 4; ++j)
      bfr[j] = *(const bf16x8*)&Bs[(wn * 64 + j * 16 + l15) * 32 + quad * 8];
#pragma unroll
    for (int i = 0; i < 4; ++i)
#pragma unroll
      for (int j = 0; j < 4; ++j)
        acc[i][j] = __builtin_amdgcn_mfma_f32_16x16x32_bf16(af[i], bfr[j],
                                                            acc[i][j], 0, 0, 0);
    __syncthreads();
  }

#pragma unroll
  for (int i = 0; i < 4; ++i) {
    int row = row0 + wm * 64 + i * 16 + quad * 4;
#pragma unroll
    for (int j = 0; j < 4; ++j) {
      int col = nb + wn * 64 + j * 16 + l15;
#pragma unroll
      for (int r = 0; r < 4; ++r)
        Out[(size_t)(row + r) * D_MODEL + col] = (bf16)acc[i][j][r];
    }
  }
}

// ---------------------------------------------------------------------------
// 3. RoPE in place on Q and K
// ---------------------------------------------------------------------------
__global__ __launch_bounds__(256) void rope_kernel(
    bf16* __restrict__ Q, bf16* __restrict__ K, const int* __restrict__ pos) {
  int idx = blockIdx.x * 256 + threadIdx.x;
  int i = idx & 31;
  int h = (idx >> 5) & 15;
  int row = idx >> 9;
  int t = row & (T_SZ - 1);
  float p = (float)pos[t];
  float freq = expf(-(float)i * 0.28782313662425f);
  float ang = p * freq;
  float s, c;
  sincosf(ang, &s, &c);
  size_t base = (size_t)row * D_MODEL + h * DH + 2 * i;
  float q1 = (float)Q[base], q2 = (float)Q[base + 1];
  Q[base]     = (bf16)(q1 * c - q2 * s);
  Q[base + 1] = (bf16)(q1 * s + q2 * c);
  float k1 = (float)K[base], k2 = (float)K[base + 1];
  K[base]     = (bf16)(k1 * c - k2 * s);
  K[base + 1] = (bf16)(k1 * s + k2 * c);
}

// ---------------------------------------------------------------------------
// 3b. V transpose: V (B*T, 1024) -> VT (B,H,DH,T)
// ---------------------------------------------------------------------------
__global__ __launch_bounds__(256) void v_transpose(
    const bf16* __restrict__ V, bf16* __restrict__ VT) {
  __shared__ bf16 tile[64][72];
  int bh = blockIdx.x;
  int tt = blockIdx.y;
  int b = bh >> 4, h = bh & 15;
  int tid = threadIdx.x;
  int rr = tid >> 3;
  int cc = (tid & 7) * 8;
#pragma unroll
  for (int p = 0; p < 2; ++p) {
    int t = rr + p * 32;
    bf16x8 v = *(const bf16x8*)&V[((size_t)b * T_SZ + tt * 64 + t) * D_MODEL +
                                  h * DH + cc];
    *(bf16x8*)&tile[t][cc] = v;
  }
  __syncthreads();
#pragma unroll
  for (int p = 0; p < 2; ++p) {
    int d = rr + p * 32;
    bf16x8 o;
#pragma unroll
    for (int j = 0; j < 8; ++j) o[j] = tile[cc + j][d];
    *(bf16x8*)&VT[((size_t)bh * DH + d) * T_SZ + tt * 64 + cc] = o;
  }
}

// ---------------------------------------------------------------------------
// 4. Causal flash attention, S^T formulation, no-running-max softmax,
//    kv-split x4 (flash-decoding style).
//    Block = 4 waves sharing one 16-row q-tile; wave w does chunks w, w+4, ...
//    Partials are UNNORMALIZED (no max) -> merge across waves is a pure add.
// ---------------------------------------------------------------------------
#define PST 72

__global__ __launch_bounds__(256) void attn_kernel(
    const bf16* __restrict__ Q, const bf16* __restrict__ K,
    const bf16* __restrict__ VT, bf16* __restrict__ AO) {
  __shared__ bf16 Pbuf[4][16 * PST];     // per-wave P transpose regions
  __shared__ float ob[3][64][16];        // waves 1..3 partial O
  __shared__ float lb[3][64];            // waves 1..3 partial l

  int bh = blockIdx.x;                    // 0..31
  int qi = 127 - (int)blockIdx.y;         // heavy q-tiles first
  int bb = bh >> 4, h = bh & 15;
  int wave = threadIdx.x >> 6, lane = threadIdx.x & 63;
  int l15 = lane & 15, quad = lane >> 4;

  int q0 = qi * 16;
  size_t grow = (size_t)bb * T_SZ + q0;

  const bf16* Qp = Q + (grow + l15) * D_MODEL + h * DH + quad * 8;
  bf16x8 bq0 = *(const bf16x8*)(Qp);
  bf16x8 bq1 = *(const bf16x8*)(Qp + 32);

  f32x4 o[4];
#pragma unroll
  for (int nt = 0; nt < 4; ++nt) o[nt] = (f32x4){0.f, 0.f, 0.f, 0.f};
  float l_i = 0.f;

  const bf16* Kbase = K + ((size_t)bb * T_SZ) * D_MODEL + h * DH + quad * 8;
  const bf16* Vbase = VT + ((size_t)bh * DH) * T_SZ;
  int nchunks = qi / 4 + 1;
  int rel = (qi & 3) * 16 + l15;          // causal boundary in last chunk

  bf16* Pw = Pbuf[wave];
  bf16x8 ka0[4], ka1[4], kb0[4], kb1[4];

  auto body = [&](bf16x8 (&kc0)[4], bf16x8 (&kc1)[4],
                  bf16x8 (&kn0)[4], bf16x8 (&kn1)[4], int t) {
    int kv0 = t * 64;
    bool last = (t == nchunks - 1);

    // ---- S^T = K · Q^T ----
    f32x4 st[4];
#pragma unroll
    for (int cs = 0; cs < 4; ++cs) {
      f32x4 s = (f32x4){0.f, 0.f, 0.f, 0.f};
      s = __builtin_amdgcn_mfma_f32_16x16x32_bf16(kc0[cs], bq0, s, 0, 0, 0);
      s = __builtin_amdgcn_mfma_f32_16x16x32_bf16(kc1[cs], bq1, s, 0, 0, 0);
      st[cs] = s;
    }

    // ---- prefetch chunk t+4 K into the other buffer ----
    if (t + 4 < nchunks) {
#pragma unroll
      for (int cs = 0; cs < 4; ++cs) {
        const bf16* Kp = Kbase + (size_t)(kv0 + 256 + cs * 16 + l15) * D_MODEL;
        kn0[cs] = *(const bf16x8*)Kp;
        kn1[cs] = *(const bf16x8*)(Kp + 32);
      }
    }

    // ---- V fragments for this chunk ----
    bf16x8 av0[4], av1[4];
#pragma unroll
    for (int nt = 0; nt < 4; ++nt) {
      const bf16* Vp = Vbase + (size_t)(nt * 16 + l15) * T_SZ + kv0 + quad * 8;
      av0[nt] = *(const bf16x8*)(Vp);
      av1[nt] = *(const bf16x8*)(Vp + 32);
    }

    // ---- p = exp(s * scale); mask above diagonal; lane-local l ----
    float ps = 0.f;
#pragma unroll
    for (int cs = 0; cs < 4; ++cs)
#pragma unroll
      for (int r = 0; r < 4; ++r) {
        float p = __expf(st[cs][r] * 0.125f);
        if (last) {
          int cl = cs * 16 + quad * 4 + r;
          p = (cl > rel) ? 0.f : p;
        }
        st[cs][r] = p;
        ps += p;
      }
    l_i += ps;

    // ---- P[q][c] -> per-wave LDS, transpose to B-operand layout ----
#pragma unroll
    for (int cs = 0; cs < 4; ++cs) {
      bf16x4 pk;
#pragma unroll
      for (int r = 0; r < 4; ++r) pk[r] = (bf16)st[cs][r];
      *(bf16x4*)&Pw[l15 * PST + cs * 16 + quad * 4] = pk;
    }
    __asm__ __volatile__("" ::: "memory");
    bf16x8 bp0 = *(const bf16x8*)&Pw[l15 * PST + quad * 8];
    bf16x8 bp1 = *(const bf16x8*)&Pw[l15 * PST + 32 + quad * 8];
    __asm__ __volatile__("" ::: "memory");

    // ---- O^T += V^T · P^T ----
#pragma unroll
    for (int nt = 0; nt < 4; ++nt) {
      o[nt] = __builtin_amdgcn_mfma_f32_16x16x32_bf16(av0[nt], bp0, o[nt], 0, 0, 0);
      o[nt] = __builtin_amdgcn_mfma_f32_16x16x32_bf16(av1[nt], bp1, o[nt], 0, 0, 0);
    }
  };

  int t = wave;
  if (t < nchunks) {
#pragma unroll
    for (int cs = 0; cs < 4; ++cs) {
      const bf16* Kp = Kbase + (size_t)(t * 64 + cs * 16 + l15) * D_MODEL;
      ka0[cs] = *(const bf16x8*)Kp;
      ka1[cs] = *(const bf16x8*)(Kp + 32);
    }
    for (;;) {
      body(ka0, ka1, kb0, kb1, t);
      t += 4; if (t >= nchunks) break;
      body(kb0, kb1, ka0, ka1, t);
      t += 4; if (t >= nchunks) break;
    }
  }

  // ---- merge partials across the 4 waves (pure add: no max used) ----
  l_i += __shfl_xor(l_i, 16);
  l_i += __shfl_xor(l_i, 32);
  if (wave != 0) {
    float* dst = &ob[wave - 1][lane][0];
#pragma unroll
    for (int nt = 0; nt < 4; ++nt) *(f32x4*)(dst + nt * 4) = o[nt];
    lb[wave - 1][lane] = l_i;
  }
  __syncthreads();
  if (wave == 0) {
#pragma unroll
    for (int w = 0; w < 3; ++w) {
      const float* src = &ob[w][lane][0];
#pragma unroll
      for (int nt = 0; nt < 4; ++nt) {
        f32x4 v = *(const f32x4*)(src + nt * 4);
#pragma unroll
        for (int r = 0; r < 4; ++r) o[nt][r] += v[r];
      }
      l_i += lb[w][lane];
    }
    float inv = 1.0f / l_i;
#pragma unroll
    for (int nt = 0; nt < 4; ++nt) {
      bf16x4 ov;
#pragma unroll
      for (int r = 0; r < 4; ++r) ov[r] = (bf16)(o[nt][r] * inv);
      *(bf16x4*)&AO[(grow + l15) * D_MODEL + h * DH + nt * 16 + quad * 4] = ov;
    }
  }
}

// ---------------------------------------------------------------------------
// 5. Output GEMM, m97 structure (unchanged)
// ---------------------------------------------------------------------------
__global__ __launch_bounds__(256) void out_gemm(
    const bf16* __restrict__ AO, const bf16* __restrict__ Wob,
    float* __restrict__ out) {
  __shared__ bf16 As[128 * 32];
  __shared__ bf16 Bs[128 * 32];

  int tid = threadIdx.x;
  int wave = tid >> 6, lane = tid & 63;
  int wm = wave >> 1, wn = wave & 1;
  int l15 = lane & 15, quad = lane >> 4;

  int row0 = blockIdx.x * 128;
  int nb = blockIdx.y * 128;

  int srow = tid >> 2;
  int schunk = tid & 3;
  const bf16* Ag = AO + (size_t)(row0 + srow) * D_MODEL + schunk * 8;
  const bf16* Bg = Wob + (size_t)(nb + srow) * D_MODEL + schunk * 8;
  bf16* Al0 = &As[srow * 32 + schunk * 8];
  bf16* Al1 = &As[(srow + 64) * 32 + schunk * 8];
  bf16* Bl0 = &Bs[srow * 32 + schunk * 8];
  bf16* Bl1 = &Bs[(srow + 64) * 32 + schunk * 8];

  f32x4 acc[4][4];
#pragma unroll
  for (int i = 0; i < 4; ++i)
#pragma unroll
    for (int j = 0; j < 4; ++j) acc[i][j] = (f32x4){0.f, 0.f, 0.f, 0.f};

  for (int k0 = 0; k0 < D_MODEL; k0 += 32) {
    async_copy16(Ag + k0, Al0);
    async_copy16(Ag + k0 + (size_t)64 * D_MODEL, Al1);
    async_copy16(Bg + k0, Bl0);
    async_copy16(Bg + k0 + (size_t)64 * D_MODEL, Bl1);
    __syncthreads();

    bf16x8 af[4], bfr[4];
#pragma unroll
    for (int i = 0; i < 4; ++i)
      af[i] = *(const bf16x8*)&As[(wm * 64 + i * 16 + l15) * 32 + quad * 8];
#pragma unroll
    for (int j = 0; j < 4; ++j)
      bfr[j] = *(const bf16x8*)&Bs[(wn * 64 + j * 16 + l15) * 32 + quad * 8];
#pragma unroll
    for (int i = 0; i < 4; ++i)
#pragma unroll
      for (int j = 0; j < 4; ++j)
        acc[i][j] = __builtin_amdgcn_mfma_f32_16x16x32_bf16(af[i], bfr[j],
                                                            acc[i][j], 0, 0, 0);
    __syncthreads();
  }

#pragma unroll
  for (int i = 0; i < 4; ++i) {
    int row = row0 + wm * 64 + i * 16 + quad * 4;
#pragma unroll
    for (int j = 0; j < 4; ++j) {
      int col = nb + wn * 64 + j * 16 + l15;
#pragma unroll
      for (int r = 0; r < 4; ++r)
        out[(size_t)(row + r) * D_MODEL + col] = acc[i][j][r];
    }
  }
}

// ---------------------------------------------------------------------------
extern "C" void kernel_launch(void* const* d_in, const int* in_sizes, int n_in,
                              void* d_out, int out_size, void* d_ws, size_t ws_size,
                              hipStream_t stream) {
  const float* X  = (const float*)d_in[0];
  const float* Wq = (const float*)d_in[1];
  const float* Wk = (const float*)d_in[2];
  const float* Wv = (const float*)d_in[3];
  const float* Wo = (const float*)d_in[4];
  const int*  pos = (const int*)d_in[5];
  float* out = (float*)d_out;

  char* w = (char*)d_ws;
  bf16* Xb  = (bf16*)w;  w += (size_t)M_ROWS * D_MODEL * 2;
  bf16* Wqb = (bf16*)w;  w += (size_t)D_MODEL * D_MODEL * 2;
  bf16* Wkb = (bf16*)w;  w += (size_t)D_MODEL * D_MODEL * 2;
  bf16* Wvb = (bf16*)w;  w += (size_t)D_MODEL * D_MODEL * 2;
  bf16* Wob = (bf16*)w;  w += (size_t)D_MODEL * D_MODEL * 2;
  bf16* Qb  = (bf16*)w;  w += (size_t)M_ROWS * D_MODEL * 2;
  bf16* Kb  = (bf16*)w;  w += (size_t)M_ROWS * D_MODEL * 2;
  bf16* Vb  = (bf16*)w;  w += (size_t)M_ROWS * D_MODEL * 2;
  bf16* AO  = (bf16*)w;  w += (size_t)M_ROWS * D_MODEL * 2;
  bf16* VT  = (bf16*)w;  w += (size_t)M_ROWS * D_MODEL * 2;

  cast_all<<<(NX + 4 * NW) / 256, 256, 0, stream>>>(X, Wq, Wk, Wv, Wo,
                                                    Xb, Wqb, Wkb, Wvb, Wob);
  qkv_gemm<<<dim3(M_ROWS / 128, 3 * D_MODEL / 128), 256, 0, stream>>>(
      Xb, Wqb, Wkb, Wvb, Qb, Kb, Vb);
  rope_kernel<<<(M_ROWS * NUM_HEADS * 32) / 256, 256, 0, stream>>>(Qb, Kb, pos);
  v_transpose<<<dim3(B_SZ * NUM_HEADS, T_SZ / 64), 256, 0, stream>>>(Vb, VT);
  attn_kernel<<<dim3(B_SZ * NUM_HEADS, T_SZ / 16), 256, 0, stream>>>(Qb, Kb, VT, AO);
  out_gemm<<<dim3(M_ROWS / 128, D_MODEL / 128), 256, 0, stream>>>(AO, Wob, out);
}

// Round 6
// 194.151 us; speedup vs baseline: 1.4249x; 1.4249x over previous
//
#include <hip/hip_runtime.h>

#define D_MODEL 1024
#define NUM_HEADS 16
#define DH 64
#define B_SZ 2
#define T_SZ 2048
#define M_ROWS (B_SZ * T_SZ)   // 4096

typedef __bf16 bf16;
typedef __bf16 bf16x4 __attribute__((ext_vector_type(4)));
typedef __bf16 bf16x8 __attribute__((ext_vector_type(8)));
typedef float f32x4 __attribute__((ext_vector_type(4)));

__device__ __forceinline__ void async_copy16(const bf16* g, bf16* l) {
  __builtin_amdgcn_global_load_lds(
      (const __attribute__((address_space(1))) void*)g,
      (__attribute__((address_space(3))) void*)l, 16, 0, 0);
}

// ---------------------------------------------------------------------------
// 1. Cast fp32 -> bf16
// ---------------------------------------------------------------------------
#define NX (M_ROWS * D_MODEL / 4)
#define NW (D_MODEL * D_MODEL / 4)

__global__ __launch_bounds__(256) void cast_all(
    const float* __restrict__ X, const float* __restrict__ Wq,
    const float* __restrict__ Wk, const float* __restrict__ Wv,
    const float* __restrict__ Wo,
    bf16* __restrict__ Xb, bf16* __restrict__ Wqb, bf16* __restrict__ Wkb,
    bf16* __restrict__ Wvb, bf16* __restrict__ Wob) {
  int i = blockIdx.x * 256 + threadIdx.x;
  const float* s; bf16* d; int off;
  if (i < NX) {
    s = X; d = Xb; off = i;
  } else {
    int j = i - NX;
    int w = j >> 18;
    off = j & (NW - 1);
    if (w == 0)      { s = Wq; d = Wqb; }
    else if (w == 1) { s = Wk; d = Wkb; }
    else if (w == 2) { s = Wv; d = Wvb; }
    else             { s = Wo; d = Wob; }
  }
  float4 v = ((const float4*)s)[off];
  bf16x4 o;
  o[0] = (bf16)v.x; o[1] = (bf16)v.y; o[2] = (bf16)v.z; o[3] = (bf16)v.w;
  ((bf16x4*)d)[off] = o;
}

// ---------------------------------------------------------------------------
// 2. QKV GEMM, m97 structure (unchanged)
// ---------------------------------------------------------------------------
__global__ __launch_bounds__(256) void qkv_gemm(
    const bf16* __restrict__ Xb,
    const bf16* __restrict__ Wqb, const bf16* __restrict__ Wkb,
    const bf16* __restrict__ Wvb,
    bf16* __restrict__ Q, bf16* __restrict__ K, bf16* __restrict__ V) {
  __shared__ bf16 As[128 * 32];
  __shared__ bf16 Bs[128 * 32];

  int tid = threadIdx.x;
  int wave = tid >> 6, lane = tid & 63;
  int wm = wave >> 1, wn = wave & 1;
  int l15 = lane & 15, quad = lane >> 4;

  int row0 = blockIdx.x * 128;
  int col0 = blockIdx.y * 128;
  int sel = col0 >> 10;
  int nb = col0 & 1023;
  const bf16* W; bf16* Out;
  if (sel == 0)      { W = Wqb; Out = Q; }
  else if (sel == 1) { W = Wkb; Out = K; }
  else               { W = Wvb; Out = V; }

  int srow = tid >> 2;
  int schunk = tid & 3;
  const bf16* Ag = Xb + (size_t)(row0 + srow) * D_MODEL + schunk * 8;
  const bf16* Bg = W + (size_t)(nb + srow) * D_MODEL + schunk * 8;
  bf16* Al0 = &As[srow * 32 + schunk * 8];
  bf16* Al1 = &As[(srow + 64) * 32 + schunk * 8];
  bf16* Bl0 = &Bs[srow * 32 + schunk * 8];
  bf16* Bl1 = &Bs[(srow + 64) * 32 + schunk * 8];

  f32x4 acc[4][4];
#pragma unroll
  for (int i = 0; i < 4; ++i)
#pragma unroll
    for (int j = 0; j < 4; ++j) acc[i][j] = (f32x4){0.f, 0.f, 0.f, 0.f};

  for (int k0 = 0; k0 < D_MODEL; k0 += 32) {
    async_copy16(Ag + k0, Al0);
    async_copy16(Ag + k0 + (size_t)64 * D_MODEL, Al1);
    async_copy16(Bg + k0, Bl0);
    async_copy16(Bg + k0 + (size_t)64 * D_MODEL, Bl1);
    __syncthreads();

    bf16x8 af[4], bfr[4];
#pragma unroll
    for (int i = 0; i < 4; ++i)
      af[i] = *(const bf16x8*)&As[(wm * 64 + i * 16 + l15) * 32 + quad * 8];
#pragma unroll
    for (int j = 0; j < 4; ++j)
      bfr[j] = *(const bf16x8*)&Bs[(wn * 64 + j * 16 + l15) * 32 + quad * 8];
#pragma unroll
    for (int i = 0; i < 4; ++i)
#pragma unroll
      for (int j = 0; j < 4; ++j)
        acc[i][j] = __builtin_amdgcn_mfma_f32_16x16x32_bf16(af[i], bfr[j],
                                                            acc[i][j], 0, 0, 0);
    __syncthreads();
  }

#pragma unroll
  for (int i = 0; i < 4; ++i) {
    int row = row0 + wm * 64 + i * 16 + quad * 4;
#pragma unroll
    for (int j = 0; j < 4; ++j) {
      int col = nb + wn * 64 + j * 16 + l15;
#pragma unroll
      for (int r = 0; r < 4; ++r)
        Out[(size_t)(row + r) * D_MODEL + col] = (bf16)acc[i][j][r];
    }
  }
}

// ---------------------------------------------------------------------------
// 3. RoPE in place on Q and K
// ---------------------------------------------------------------------------
__global__ __launch_bounds__(256) void rope_kernel(
    bf16* __restrict__ Q, bf16* __restrict__ K, const int* __restrict__ pos) {
  int idx = blockIdx.x * 256 + threadIdx.x;
  int i = idx & 31;
  int h = (idx >> 5) & 15;
  int row = idx >> 9;
  int t = row & (T_SZ - 1);
  float p = (float)pos[t];
  float freq = expf(-(float)i * 0.28782313662425f);
  float ang = p * freq;
  float s, c;
  sincosf(ang, &s, &c);
  size_t base = (size_t)row * D_MODEL + h * DH + 2 * i;
  float q1 = (float)Q[base], q2 = (float)Q[base + 1];
  Q[base]     = (bf16)(q1 * c - q2 * s);
  Q[base + 1] = (bf16)(q1 * s + q2 * c);
  float k1 = (float)K[base], k2 = (float)K[base + 1];
  K[base]     = (bf16)(k1 * c - k2 * s);
  K[base + 1] = (bf16)(k1 * s + k2 * c);
}

// ---------------------------------------------------------------------------
// 3b. V transpose: V (B*T, 1024) -> VT (B,H,DH,T)
// ---------------------------------------------------------------------------
__global__ __launch_bounds__(256) void v_transpose(
    const bf16* __restrict__ V, bf16* __restrict__ VT) {
  __shared__ bf16 tile[64][72];
  int bh = blockIdx.x;
  int tt = blockIdx.y;
  int b = bh >> 4, h = bh & 15;
  int tid = threadIdx.x;
  int rr = tid >> 3;
  int cc = (tid & 7) * 8;
#pragma unroll
  for (int p = 0; p < 2; ++p) {
    int t = rr + p * 32;
    bf16x8 v = *(const bf16x8*)&V[((size_t)b * T_SZ + tt * 64 + t) * D_MODEL +
                                  h * DH + cc];
    *(bf16x8*)&tile[t][cc] = v;
  }
  __syncthreads();
#pragma unroll
  for (int p = 0; p < 2; ++p) {
    int d = rr + p * 32;
    bf16x8 o;
#pragma unroll
    for (int j = 0; j < 8; ++j) o[j] = tile[cc + j][d];
    *(bf16x8*)&VT[((size_t)bh * DH + d) * T_SZ + tt * 64 + cc] = o;
  }
}

// ---------------------------------------------------------------------------
// 4. Causal flash attention: block-cooperative LDS staging (m97-style).
//    Block = 4 waves, q-tile 64 (wave w owns rows w*16..+15). kv chunks of 64
//    staged to LDS by all 256 threads via global_load_lds (K as two 64x32
//    d-half-tiles, V^T as two 64x32 c-half-tiles). S^T per-wave formulation,
//    no-running-max unnormalized softmax; P transpose via per-wave LDS.
// ---------------------------------------------------------------------------
#define PST 72

__global__ __launch_bounds__(256) void attn_kernel(
    const bf16* __restrict__ Q, const bf16* __restrict__ K,
    const bf16* __restrict__ VT, bf16* __restrict__ AO) {
  __shared__ bf16 Kt0[64 * 32], Kt1[64 * 32];   // K rows kv0..+63, d 0..31 / 32..63
  __shared__ bf16 Vt0[64 * 32], Vt1[64 * 32];   // VT rows d 0..63, c 0..31 / 32..63
  __shared__ bf16 Pbuf[4][16 * PST];

  int bh = blockIdx.x;                    // 0..31
  int qi = 31 - (int)blockIdx.y;          // q-tile of 64, heavy first
  int bb = bh >> 4, h = bh & 15;
  int tid = threadIdx.x;
  int wave = tid >> 6, lane = tid & 63;
  int l15 = lane & 15, quad = lane >> 4;

  int q0 = qi * 64 + wave * 16;
  size_t grow = (size_t)bb * T_SZ + q0;

  const bf16* Qp = Q + (grow + l15) * D_MODEL + h * DH + quad * 8;
  bf16x8 bq0 = *(const bf16x8*)(Qp);
  bf16x8 bq1 = *(const bf16x8*)(Qp + 32);

  f32x4 o[4];
#pragma unroll
  for (int nt = 0; nt < 4; ++nt) o[nt] = (f32x4){0.f, 0.f, 0.f, 0.f};
  float l_i = 0.f;

  // staging: 256 threads x 16 B fill one 64x32 half-tile per call
  int srow = tid >> 2;                    // 0..63
  int sch = tid & 3;                      // 16B chunk
  const bf16* Kg = K + ((size_t)bb * T_SZ + srow) * D_MODEL + h * DH + sch * 8;
  const bf16* Vg = VT + ((size_t)bh * DH + srow) * T_SZ + sch * 8;
  bf16* Kl0 = &Kt0[srow * 32 + sch * 8];
  bf16* Kl1 = &Kt1[srow * 32 + sch * 8];
  bf16* Vl0 = &Vt0[srow * 32 + sch * 8];
  bf16* Vl1 = &Vt1[srow * 32 + sch * 8];

  bf16* Pw = Pbuf[wave];
  int nchunks = qi + 1;
  int rel = wave * 16 + l15;              // causal boundary (last chunk)

  for (int t = 0; t < nchunks; ++t) {
    int kv0 = t * 64;

    async_copy16(Kg + (size_t)kv0 * D_MODEL, Kl0);
    async_copy16(Kg + (size_t)kv0 * D_MODEL + 32, Kl1);
    async_copy16(Vg + kv0, Vl0);
    async_copy16(Vg + kv0 + 32, Vl1);
    __syncthreads();

    // ---- S^T = K · Q^T  (A-frags from LDS K tile) ----
    f32x4 st[4];
#pragma unroll
    for (int cs = 0; cs < 4; ++cs) {
      bf16x8 ak0 = *(const bf16x8*)&Kt0[(cs * 16 + l15) * 32 + quad * 8];
      bf16x8 ak1 = *(const bf16x8*)&Kt1[(cs * 16 + l15) * 32 + quad * 8];
      f32x4 s = (f32x4){0.f, 0.f, 0.f, 0.f};
      s = __builtin_amdgcn_mfma_f32_16x16x32_bf16(ak0, bq0, s, 0, 0, 0);
      s = __builtin_amdgcn_mfma_f32_16x16x32_bf16(ak1, bq1, s, 0, 0, 0);
      st[cs] = s;
    }

    // ---- p = exp(s*scale); mask above diagonal on last chunk ----
    bool last = (t == nchunks - 1);
    float ps = 0.f;
#pragma unroll
    for (int cs = 0; cs < 4; ++cs)
#pragma unroll
      for (int r = 0; r < 4; ++r) {
        float p = __expf(st[cs][r] * 0.125f);
        if (last) {
          int cl = cs * 16 + quad * 4 + r;
          p = (cl > rel) ? 0.f : p;
        }
        st[cs][r] = p;
        ps += p;
      }
    l_i += ps;

    // ---- P[q][c] -> per-wave LDS, transpose to B-operand layout ----
#pragma unroll
    for (int cs = 0; cs < 4; ++cs) {
      bf16x4 pk;
#pragma unroll
      for (int r = 0; r < 4; ++r) pk[r] = (bf16)st[cs][r];
      *(bf16x4*)&Pw[l15 * PST + cs * 16 + quad * 4] = pk;
    }
    __asm__ __volatile__("" ::: "memory");
    bf16x8 bp0 = *(const bf16x8*)&Pw[l15 * PST + quad * 8];
    bf16x8 bp1 = *(const bf16x8*)&Pw[l15 * PST + 32 + quad * 8];
    __asm__ __volatile__("" ::: "memory");

    // ---- O^T += V^T · P^T  (A-frags from LDS V tile) ----
#pragma unroll
    for (int nt = 0; nt < 4; ++nt) {
      bf16x8 av0 = *(const bf16x8*)&Vt0[(nt * 16 + l15) * 32 + quad * 8];
      bf16x8 av1 = *(const bf16x8*)&Vt1[(nt * 16 + l15) * 32 + quad * 8];
      o[nt] = __builtin_amdgcn_mfma_f32_16x16x32_bf16(av0, bp0, o[nt], 0, 0, 0);
      o[nt] = __builtin_amdgcn_mfma_f32_16x16x32_bf16(av1, bp1, o[nt], 0, 0, 0);
    }
    __syncthreads();
  }

  // ---- l reduction across quads, normalize, store ----
  l_i += __shfl_xor(l_i, 16);
  l_i += __shfl_xor(l_i, 32);
  float inv = 1.0f / l_i;
#pragma unroll
  for (int nt = 0; nt < 4; ++nt) {
    bf16x4 ov;
#pragma unroll
    for (int r = 0; r < 4; ++r) ov[r] = (bf16)(o[nt][r] * inv);
    *(bf16x4*)&AO[(grow + l15) * D_MODEL + h * DH + nt * 16 + quad * 4] = ov;
  }
}

// ---------------------------------------------------------------------------
// 5. Output GEMM, m97 structure (unchanged)
// ---------------------------------------------------------------------------
__global__ __launch_bounds__(256) void out_gemm(
    const bf16* __restrict__ AO, const bf16* __restrict__ Wob,
    float* __restrict__ out) {
  __shared__ bf16 As[128 * 32];
  __shared__ bf16 Bs[128 * 32];

  int tid = threadIdx.x;
  int wave = tid >> 6, lane = tid & 63;
  int wm = wave >> 1, wn = wave & 1;
  int l15 = lane & 15, quad = lane >> 4;

  int row0 = blockIdx.x * 128;
  int nb = blockIdx.y * 128;

  int srow = tid >> 2;
  int schunk = tid & 3;
  const bf16* Ag = AO + (size_t)(row0 + srow) * D_MODEL + schunk * 8;
  const bf16* Bg = Wob + (size_t)(nb + srow) * D_MODEL + schunk * 8;
  bf16* Al0 = &As[srow * 32 + schunk * 8];
  bf16* Al1 = &As[(srow + 64) * 32 + schunk * 8];
  bf16* Bl0 = &Bs[srow * 32 + schunk * 8];
  bf16* Bl1 = &Bs[(srow + 64) * 32 + schunk * 8];

  f32x4 acc[4][4];
#pragma unroll
  for (int i = 0; i < 4; ++i)
#pragma unroll
    for (int j = 0; j < 4; ++j) acc[i][j] = (f32x4){0.f, 0.f, 0.f, 0.f};

  for (int k0 = 0; k0 < D_MODEL; k0 += 32) {
    async_copy16(Ag + k0, Al0);
    async_copy16(Ag + k0 + (size_t)64 * D_MODEL, Al1);
    async_copy16(Bg + k0, Bl0);
    async_copy16(Bg + k0 + (size_t)64 * D_MODEL, Bl1);
    __syncthreads();

    bf16x8 af[4], bfr[4];
#pragma unroll
    for (int i = 0; i < 4; ++i)
      af[i] = *(const bf16x8*)&As[(wm * 64 + i * 16 + l15) * 32 + quad * 8];
#pragma unroll
    for (int j = 0; j < 4; ++j)
      bfr[j] = *(const bf16x8*)&Bs[(wn * 64 + j * 16 + l15) * 32 + quad * 8];
#pragma unroll
    for (int i = 0; i < 4; ++i)
#pragma unroll
      for (int j = 0; j < 4; ++j)
        acc[i][j] = __builtin_amdgcn_mfma_f32_16x16x32_bf16(af[i], bfr[j],
                                                            acc[i][j], 0, 0, 0);
    __syncthreads();
  }

#pragma unroll
  for (int i = 0; i < 4; ++i) {
    int row = row0 + wm * 64 + i * 16 + quad * 4;
#pragma unroll
    for (int j = 0; j < 4; ++j) {
      int col = nb + wn * 64 + j * 16 + l15;
#pragma unroll
      for (int r = 0; r < 4; ++r)
        out[(size_t)(row + r) * D_MODEL + col] = acc[i][j][r];
    }
  }
}

// ---------------------------------------------------------------------------
extern "C" void kernel_launch(void* const* d_in, const int* in_sizes, int n_in,
                              void* d_out, int out_size, void* d_ws, size_t ws_size,
                              hipStream_t stream) {
  const float* X  = (const float*)d_in[0];
  const float* Wq = (const float*)d_in[1];
  const float* Wk = (const float*)d_in[2];
  const float* Wv = (const float*)d_in[3];
  const float* Wo = (const float*)d_in[4];
  const int*  pos = (const int*)d_in[5];
  float* out = (float*)d_out;

  char* w = (char*)d_ws;
  bf16* Xb  = (bf16*)w;  w += (size_t)M_ROWS * D_MODEL * 2;
  bf16* Wqb = (bf16*)w;  w += (size_t)D_MODEL * D_MODEL * 2;
  bf16* Wkb = (bf16*)w;  w += (size_t)D_MODEL * D_MODEL * 2;
  bf16* Wvb = (bf16*)w;  w += (size_t)D_MODEL * D_MODEL * 2;
  bf16* Wob = (bf16*)w;  w += (size_t)D_MODEL * D_MODEL * 2;
  bf16* Qb  = (bf16*)w;  w += (size_t)M_ROWS * D_MODEL * 2;
  bf16* Kb  = (bf16*)w;  w += (size_t)M_ROWS * D_MODEL * 2;
  bf16* Vb  = (bf16*)w;  w += (size_t)M_ROWS * D_MODEL * 2;
  bf16* AO  = (bf16*)w;  w += (size_t)M_ROWS * D_MODEL * 2;
  bf16* VT  = (bf16*)w;  w += (size_t)M_ROWS * D_MODEL * 2;

  cast_all<<<(NX + 4 * NW) / 256, 256, 0, stream>>>(X, Wq, Wk, Wv, Wo,
                                                    Xb, Wqb, Wkb, Wvb, Wob);
  qkv_gemm<<<dim3(M_ROWS / 128, 3 * D_MODEL / 128), 256, 0, stream>>>(
      Xb, Wqb, Wkb, Wvb, Qb, Kb, Vb);
  rope_kernel<<<(M_ROWS * NUM_HEADS * 32) / 256, 256, 0, stream>>>(Qb, Kb, pos);
  v_transpose<<<dim3(B_SZ * NUM_HEADS, T_SZ / 64), 256, 0, stream>>>(Vb, VT);
  attn_kernel<<<dim3(B_SZ * NUM_HEADS, T_SZ / 64), 256, 0, stream>>>(Qb, Kb, VT, AO);
  out_gemm<<<dim3(M_ROWS / 128, D_MODEL / 128), 256, 0, stream>>>(AO, Wob, out);
}